// Round 2
// baseline (722.459 us; speedup 1.0000x reference)
//
#include <hip/hip_runtime.h>
#include <math.h>

#define P_DIM 1024
#define R_DIM 128
#define M_DIM 128

// One block per output row i. Three phases:
//   A: scores[j] = dot(rela[i,j,:], att_w)            -> LDS  (streams 512 KB/block)
//   B: masked softmax over j (exact ref semantics: non-neighbors become -1e-6
//      and DO contribute to the denominator; weights then zeroed)
//   C: out[i,:] = weights[i,:] @ hidden  (hidden is L2-resident, 512 KB)
__global__ __launch_bounds__(256) void fused_kernel(
    const float* __restrict__ rela,
    const int*   __restrict__ nei,
    const float* __restrict__ hidden,
    const float* __restrict__ att_w,
    const float* __restrict__ att_b,
    float* __restrict__ out)
{
    __shared__ float  s_lds[P_DIM];   // scores, then softmax weights (4 KB)
    __shared__ float  red[8];         // cross-wave reduce scratch
    __shared__ float2 part[4][64];    // phase-C partials (2 KB)

    const int t   = threadIdx.x;
    const int i   = blockIdx.x;
    const int g   = t >> 5;           // 8 groups of 32 lanes
    const int l32 = t & 31;

    // ---- Phase A: scores into LDS ----
    const float4 w4 = reinterpret_cast<const float4*>(att_w)[l32];
    const float4* rrow =
        reinterpret_cast<const float4*>(rela + (size_t)i * (P_DIM * R_DIM));

    #pragma unroll 4
    for (int jq = 0; jq < 128; ++jq) {
        const int j = jq * 8 + g;                    // block covers rows jq*8..+7 (4 KB contiguous)
        const float4 v = rrow[(size_t)j * 32 + l32]; // wave reads 1 KB contiguous
        float s = v.x * w4.x + v.y * w4.y + v.z * w4.z + v.w * w4.w;
        s += __shfl_xor(s, 16);
        s += __shfl_xor(s, 8);
        s += __shfl_xor(s, 4);
        s += __shfl_xor(s, 2);
        s += __shfl_xor(s, 1);
        if (l32 == 0) s_lds[j] = s;
    }
    __syncthreads();

    // ---- Phase B: masked softmax (thread owns j = 4t..4t+3) ----
    const float bias = att_b[0];
    const int4  n4 = reinterpret_cast<const int4*>(nei + (size_t)i * P_DIM)[t];
    const float4 sv = reinterpret_cast<const float4*>(s_lds)[t];

    float v0 = (n4.x > 0) ? sv.x + bias : -1e-6f;
    float v1 = (n4.y > 0) ? sv.y + bias : -1e-6f;
    float v2 = (n4.z > 0) ? sv.z + bias : -1e-6f;
    float v3 = (n4.w > 0) ? sv.w + bias : -1e-6f;

    float lmax = fmaxf(fmaxf(v0, v1), fmaxf(v2, v3));
    #pragma unroll
    for (int off = 32; off >= 1; off >>= 1)
        lmax = fmaxf(lmax, __shfl_xor(lmax, off));
    if ((t & 63) == 0) red[t >> 6] = lmax;
    __syncthreads();
    const float gmax = fmaxf(fmaxf(red[0], red[1]), fmaxf(red[2], red[3]));

    const float e0 = __expf(v0 - gmax);
    const float e1 = __expf(v1 - gmax);
    const float e2 = __expf(v2 - gmax);
    const float e3 = __expf(v3 - gmax);
    float lsum = (e0 + e1) + (e2 + e3);
    #pragma unroll
    for (int off = 32; off >= 1; off >>= 1)
        lsum += __shfl_xor(lsum, off);
    if ((t & 63) == 0) red[4 + (t >> 6)] = lsum;
    __syncthreads();
    const float inv = 1.0f / (red[4] + red[5] + red[6] + red[7]);

    float4 wv;
    wv.x = (n4.x > 0) ? e0 * inv : 0.f;
    wv.y = (n4.y > 0) ? e1 * inv : 0.f;
    wv.z = (n4.z > 0) ? e2 * inv : 0.f;
    wv.w = (n4.w > 0) ? e3 * inv : 0.f;
    __syncthreads();                                  // all reads of s_lds done
    reinterpret_cast<float4*>(s_lds)[t] = wv;
    __syncthreads();

    // ---- Phase C: out[i,:] = weights @ hidden ----
    // wave q owns j in [q*256, q*256+256); lane owns float2 column c2
    const int c2 = t & 63;
    const int q  = t >> 6;
    const float2* h2 = reinterpret_cast<const float2*>(hidden);

    float2 acc = make_float2(0.f, 0.f);
    const int jb = q * 256;
    #pragma unroll 4
    for (int jj = 0; jj < 256; ++jj) {
        const int j = jb + jj;
        const float wj = s_lds[j];                    // wave-uniform LDS broadcast
        const float2 h = h2[(size_t)j * 64 + c2];     // 512 B coalesced, L2-hot
        acc.x += wj * h.x;
        acc.y += wj * h.y;
    }
    part[q][c2] = acc;
    __syncthreads();

    if (t < 64) {
        float2 s = part[0][t];
        #pragma unroll
        for (int qq = 1; qq < 4; ++qq) {
            s.x += part[qq][t].x;
            s.y += part[qq][t].y;
        }
        reinterpret_cast<float2*>(out + (size_t)i * M_DIM)[t] = s;
    }
}

// ---------------------------------------------------------------------------
extern "C" void kernel_launch(void* const* d_in, const int* in_sizes, int n_in,
                              void* d_out, int out_size, void* d_ws, size_t ws_size,
                              hipStream_t stream) {
    const float* hidden = (const float*)d_in[0];   // [1024,128]
    const float* rela   = (const float*)d_in[1];   // [1024,1024,128]
    // d_in[2] corr_index: unused by the reference
    const int*   nei    = (const int*)d_in[3];     // [1024,1024]
    const float* att_w  = (const float*)d_in[4];   // [128]
    const float* att_b  = (const float*)d_in[5];   // [1]
    float* out = (float*)d_out;                    // [1024,128]

    fused_kernel<<<P_DIM, 256, 0, stream>>>(rela, nei, hidden, att_w, att_b, out);
}

// Round 3
// 703.923 us; speedup vs baseline: 1.0263x; 1.0263x over previous
//
#include <hip/hip_runtime.h>
#include <math.h>

#define P_DIM 1024
#define R_DIM 128
#define M_DIM 128

// ---------------------------------------------------------------------------
// Phase 1: scores[i,j] = dot(rela[i,j,:], att_w) + att_b
// 4096 blocks x 256 threads; block computes 256 consecutive pair-scores.
// Wave handles 4 pairs per iteration: 16 lanes/pair, 2 float4/lane,
// 4-step shfl butterfly. 16 iterations, unroll 4 -> 8 loads in flight/thread.
// Scores staged in LDS, written out as one coalesced 1 KB burst.
// ---------------------------------------------------------------------------
__global__ __launch_bounds__(256) void scores_kernel(
    const float* __restrict__ rela,
    const float* __restrict__ att_w,
    const float* __restrict__ att_b,
    float* __restrict__ scores)
{
    __shared__ float s_tile[256];

    const int t     = threadIdx.x;
    const int wave  = t >> 6;
    const int lane  = t & 63;
    const int p_loc = lane >> 4;       // which of the wave's 4 pairs
    const int l16   = lane & 15;       // lane within the 16-lane pair group

    const float4 w_lo = reinterpret_cast<const float4*>(att_w)[l16];
    const float4 w_hi = reinterpret_cast<const float4*>(att_w)[l16 + 16];
    const float  bias = att_b[0];

    const float4* r4 = reinterpret_cast<const float4*>(rela);
    const int pair_base = blockIdx.x * 256 + wave * 4 + p_loc;

    #pragma unroll 4
    for (int it = 0; it < 16; ++it) {
        const int pair = pair_base + it * 16;          // 16 pairs/block/iter
        const size_t b = (size_t)pair * 32;            // float4 units
        const float4 v0 = r4[b + l16];
        const float4 v1 = r4[b + l16 + 16];
        float s = v0.x * w_lo.x + v0.y * w_lo.y + v0.z * w_lo.z + v0.w * w_lo.w
                + v1.x * w_hi.x + v1.y * w_hi.y + v1.z * w_hi.z + v1.w * w_hi.w;
        s += __shfl_xor(s, 8);
        s += __shfl_xor(s, 4);
        s += __shfl_xor(s, 2);
        s += __shfl_xor(s, 1);
        if (l16 == 0) s_tile[it * 16 + wave * 4 + p_loc] = s + bias;
    }
    __syncthreads();

    if (t < 64)
        reinterpret_cast<float4*>(scores)[blockIdx.x * 64 + t] =
            reinterpret_cast<const float4*>(s_tile)[t];
}

// ---------------------------------------------------------------------------
// Phase 2 (unchanged from R1): masked softmax over j (exact ref semantics:
// non-neighbors become -1e-6 and DO contribute to the denominator; weights
// then zeroed), followed by out[i,:] = weights[i,:] @ hidden.
// 4 rows per block, 256 threads (one wave per row for the softmax).
// ---------------------------------------------------------------------------
__device__ __forceinline__ float fcomp(const float4& v, int k) {
    return k == 0 ? v.x : k == 1 ? v.y : k == 2 ? v.z : v.w;
}

__global__ __launch_bounds__(256) void attn_kernel(
    const float* __restrict__ scores,
    const int* __restrict__ nei,
    const float* __restrict__ hidden,
    float* __restrict__ out)
{
    __shared__ float  wsm[4][P_DIM];       // softmax weights, 16 KB
    __shared__ float4 part[4][8][32];      // matmul partials, 16 KB

    const int t    = threadIdx.x;
    const int wid  = t >> 6;               // wave id == row within block
    const int lane = t & 63;
    const int i0   = blockIdx.x << 2;
    const int i    = i0 + wid;

    // ---- per-wave softmax of row i (16 elements per lane) ----
    const float4* s4p = reinterpret_cast<const float4*>(scores + (size_t)i * P_DIM);
    const int4*   n4p = reinterpret_cast<const int4*>(nei + (size_t)i * P_DIM);

    float pv[16];
    unsigned mbits = 0;
    float lmax = -3.0e38f;
    #pragma unroll
    for (int c = 0; c < 4; ++c) {
        const int idx = c * 64 + lane;     // float4 index within row
        const float4 s4 = s4p[idx];
        const int4   n4 = n4p[idx];
        const float v0 = (n4.x > 0) ? s4.x : -1e-6f;
        const float v1 = (n4.y > 0) ? s4.y : -1e-6f;
        const float v2 = (n4.z > 0) ? s4.z : -1e-6f;
        const float v3 = (n4.w > 0) ? s4.w : -1e-6f;
        mbits |= ((n4.x > 0) ? 1u : 0u) << (c * 4 + 0);
        mbits |= ((n4.y > 0) ? 1u : 0u) << (c * 4 + 1);
        mbits |= ((n4.z > 0) ? 1u : 0u) << (c * 4 + 2);
        mbits |= ((n4.w > 0) ? 1u : 0u) << (c * 4 + 3);
        pv[c * 4 + 0] = v0; pv[c * 4 + 1] = v1;
        pv[c * 4 + 2] = v2; pv[c * 4 + 3] = v3;
        lmax = fmaxf(lmax, fmaxf(fmaxf(v0, v1), fmaxf(v2, v3)));
    }
    #pragma unroll
    for (int off = 32; off >= 1; off >>= 1)
        lmax = fmaxf(lmax, __shfl_xor(lmax, off));

    float lsum = 0.f;
    #pragma unroll
    for (int k = 0; k < 16; ++k) {
        const float e = __expf(pv[k] - lmax);
        pv[k] = e;
        lsum += e;
    }
    #pragma unroll
    for (int off = 32; off >= 1; off >>= 1)
        lsum += __shfl_xor(lsum, off);
    const float inv = 1.0f / lsum;

    #pragma unroll
    for (int c = 0; c < 4; ++c) {
        const int idx = c * 64 + lane;
        float4 o;
        o.x = ((mbits >> (c * 4 + 0)) & 1u) ? pv[c * 4 + 0] * inv : 0.f;
        o.y = ((mbits >> (c * 4 + 1)) & 1u) ? pv[c * 4 + 1] * inv : 0.f;
        o.z = ((mbits >> (c * 4 + 2)) & 1u) ? pv[c * 4 + 2] * inv : 0.f;
        o.w = ((mbits >> (c * 4 + 3)) & 1u) ? pv[c * 4 + 3] * inv : 0.f;
        reinterpret_cast<float4*>(wsm[wid])[idx] = o;
    }
    __syncthreads();

    // ---- matmul: thread owns float4-column c4, j-group h (128 j's) ----
    const int c4 = t & 31;
    const int h  = t >> 5;

    float4 acc[4];
    #pragma unroll
    for (int r = 0; r < 4; ++r) acc[r] = make_float4(0.f, 0.f, 0.f, 0.f);

    const int jbase = h * 128;
    #pragma unroll 2
    for (int jq = 0; jq < 32; ++jq) {
        const int j = jbase + jq * 4;
        float4 wq[4];
        #pragma unroll
        for (int r = 0; r < 4; ++r)
            wq[r] = *reinterpret_cast<const float4*>(&wsm[r][j]);  // LDS broadcast b128
        float4 hv[4];
        #pragma unroll
        for (int k = 0; k < 4; ++k)
            hv[k] = reinterpret_cast<const float4*>(hidden + (size_t)(j + k) * M_DIM)[c4];
        #pragma unroll
        for (int r = 0; r < 4; ++r) {
            #pragma unroll
            for (int k = 0; k < 4; ++k) {
                const float wc = fcomp(wq[r], k);
                acc[r].x += wc * hv[k].x;
                acc[r].y += wc * hv[k].y;
                acc[r].z += wc * hv[k].z;
                acc[r].w += wc * hv[k].w;
            }
        }
    }

    #pragma unroll
    for (int r = 0; r < 4; ++r) part[r][h][c4] = acc[r];
    __syncthreads();

    if (t < 128) {
        const int r = t >> 5;
        const int c = t & 31;
        float4 sum = part[r][0][c];
        #pragma unroll
        for (int hh = 1; hh < 8; ++hh) {
            const float4 p = part[r][hh][c];
            sum.x += p.x; sum.y += p.y; sum.z += p.z; sum.w += p.w;
        }
        reinterpret_cast<float4*>(out + (size_t)(i0 + r) * M_DIM)[c] = sum;
    }
}

// ---------------------------------------------------------------------------
extern "C" void kernel_launch(void* const* d_in, const int* in_sizes, int n_in,
                              void* d_out, int out_size, void* d_ws, size_t ws_size,
                              hipStream_t stream) {
    const float* hidden = (const float*)d_in[0];   // [1024,128]
    const float* rela   = (const float*)d_in[1];   // [1024,1024,128]
    // d_in[2] corr_index: unused by the reference
    const int*   nei    = (const int*)d_in[3];     // [1024,1024]
    const float* att_w  = (const float*)d_in[4];   // [128]
    const float* att_b  = (const float*)d_in[5];   // [1]
    float* out    = (float*)d_out;                 // [1024,128]
    float* scores = (float*)d_ws;                  // [1024*1024] fp32 = 4 MB scratch

    scores_kernel<<<4096, 256, 0, stream>>>(rela, att_w, att_b, scores);
    attn_kernel<<<P_DIM / 4, 256, 0, stream>>>(scores, nei, hidden, out);
}

// Round 4
// 659.653 us; speedup vs baseline: 1.0952x; 1.0671x over previous
//
#include <hip/hip_runtime.h>
#include <math.h>

#define P_DIM 1024
#define R_DIM 128
#define M_DIM 128

// ---------------------------------------------------------------------------
// Phase 1: scores[p] = nei[p]>0 ? dot(rela[p,:], att_w)+att_b : -1e-6
// KEY: ~50% of pairs have nei==0 -> their 512 B rela rows are NEVER loaded.
// Wave owns 64 consecutive pairs. Coalesced nei prefetch (1 int/lane),
// then 32 iters x 2 pairs (32 lanes/pair, 1 float4/lane, exec-masked load),
// 5-shfl butterfly, park result in owner lane, coalesced 256 B store at end.
// ---------------------------------------------------------------------------
__global__ __launch_bounds__(256) void scores_kernel(
    const float* __restrict__ rela,
    const int*   __restrict__ nei,
    const float* __restrict__ att_w,
    const float* __restrict__ att_b,
    float* __restrict__ scores)
{
    const int t    = threadIdx.x;
    const int wv   = t >> 6;            // wave within block (0..3)
    const int lane = t & 63;
    const int half = lane >> 5;         // which of the 2 concurrent pairs
    const int l32  = lane & 31;

    const float4 w4   = reinterpret_cast<const float4*>(att_w)[l32];
    const float  bias = att_b[0];
    const float4* r4  = reinterpret_cast<const float4*>(rela);

    const int W     = blockIdx.x * 4 + wv;   // global wave id (16384 waves)
    const int pbase = W * 64;                // wave owns pairs [pbase, pbase+64)

    // coalesced nei prefetch: lane k holds nei for pair pbase+k
    const int n_all = nei[pbase + lane];

    float my_score = -1e-6f;                 // lane k's output for pair pbase+k

    // half h processes pairs pbase + 32*h + it  (owner lane = 32*h + it)
    #pragma unroll 8
    for (int it = 0; it < 32; ++it) {
        const int n = __shfl(n_all, it + 32 * half);   // per-half uniform
        const int pair = pbase + 32 * half + it;
        float s = 0.f;
        if (n > 0) {                                    // exec-masked: skips 512 B chunk
            const float4 v = r4[(size_t)pair * 32 + l32];
            s = v.x * w4.x + v.y * w4.y + v.z * w4.z + v.w * w4.w;
        }
        s += __shfl_xor(s, 16);
        s += __shfl_xor(s, 8);
        s += __shfl_xor(s, 4);
        s += __shfl_xor(s, 2);
        s += __shfl_xor(s, 1);
        // all 32 lanes of the half now hold the pair's sum; park in owner lane
        if (l32 == it && n > 0) my_score = s + bias;
    }

    scores[pbase + lane] = my_score;         // coalesced 256 B store
}

// ---------------------------------------------------------------------------
// Phase 2 (unchanged, verified): masked softmax over j (exact ref semantics:
// non-neighbors become -1e-6 and DO contribute to the denominator; weights
// then zeroed), followed by out[i,:] = weights[i,:] @ hidden.
// 4 rows per block, 256 threads (one wave per row for the softmax).
// ---------------------------------------------------------------------------
__device__ __forceinline__ float fcomp(const float4& v, int k) {
    return k == 0 ? v.x : k == 1 ? v.y : k == 2 ? v.z : v.w;
}

__global__ __launch_bounds__(256) void attn_kernel(
    const float* __restrict__ scores,
    const int* __restrict__ nei,
    const float* __restrict__ hidden,
    float* __restrict__ out)
{
    __shared__ float  wsm[4][P_DIM];       // softmax weights, 16 KB
    __shared__ float4 part[4][8][32];      // matmul partials, 16 KB

    const int t    = threadIdx.x;
    const int wid  = t >> 6;               // wave id == row within block
    const int lane = t & 63;
    const int i0   = blockIdx.x << 2;
    const int i    = i0 + wid;

    // ---- per-wave softmax of row i (16 elements per lane) ----
    const float4* s4p = reinterpret_cast<const float4*>(scores + (size_t)i * P_DIM);
    const int4*   n4p = reinterpret_cast<const int4*>(nei + (size_t)i * P_DIM);

    float pv[16];
    unsigned mbits = 0;
    float lmax = -3.0e38f;
    #pragma unroll
    for (int c = 0; c < 4; ++c) {
        const int idx = c * 64 + lane;     // float4 index within row
        const float4 s4 = s4p[idx];
        const int4   n4 = n4p[idx];
        const float v0 = (n4.x > 0) ? s4.x : -1e-6f;
        const float v1 = (n4.y > 0) ? s4.y : -1e-6f;
        const float v2 = (n4.z > 0) ? s4.z : -1e-6f;
        const float v3 = (n4.w > 0) ? s4.w : -1e-6f;
        mbits |= ((n4.x > 0) ? 1u : 0u) << (c * 4 + 0);
        mbits |= ((n4.y > 0) ? 1u : 0u) << (c * 4 + 1);
        mbits |= ((n4.z > 0) ? 1u : 0u) << (c * 4 + 2);
        mbits |= ((n4.w > 0) ? 1u : 0u) << (c * 4 + 3);
        pv[c * 4 + 0] = v0; pv[c * 4 + 1] = v1;
        pv[c * 4 + 2] = v2; pv[c * 4 + 3] = v3;
        lmax = fmaxf(lmax, fmaxf(fmaxf(v0, v1), fmaxf(v2, v3)));
    }
    #pragma unroll
    for (int off = 32; off >= 1; off >>= 1)
        lmax = fmaxf(lmax, __shfl_xor(lmax, off));

    float lsum = 0.f;
    #pragma unroll
    for (int k = 0; k < 16; ++k) {
        const float e = __expf(pv[k] - lmax);
        pv[k] = e;
        lsum += e;
    }
    #pragma unroll
    for (int off = 32; off >= 1; off >>= 1)
        lsum += __shfl_xor(lsum, off);
    const float inv = 1.0f / lsum;

    #pragma unroll
    for (int c = 0; c < 4; ++c) {
        const int idx = c * 64 + lane;
        float4 o;
        o.x = ((mbits >> (c * 4 + 0)) & 1u) ? pv[c * 4 + 0] * inv : 0.f;
        o.y = ((mbits >> (c * 4 + 1)) & 1u) ? pv[c * 4 + 1] * inv : 0.f;
        o.z = ((mbits >> (c * 4 + 2)) & 1u) ? pv[c * 4 + 2] * inv : 0.f;
        o.w = ((mbits >> (c * 4 + 3)) & 1u) ? pv[c * 4 + 3] * inv : 0.f;
        reinterpret_cast<float4*>(wsm[wid])[idx] = o;
    }
    __syncthreads();

    // ---- matmul: thread owns float4-column c4, j-group h (128 j's) ----
    const int c4 = t & 31;
    const int h  = t >> 5;

    float4 acc[4];
    #pragma unroll
    for (int r = 0; r < 4; ++r) acc[r] = make_float4(0.f, 0.f, 0.f, 0.f);

    const int jbase = h * 128;
    #pragma unroll 2
    for (int jq = 0; jq < 32; ++jq) {
        const int j = jbase + jq * 4;
        float4 wq[4];
        #pragma unroll
        for (int r = 0; r < 4; ++r)
            wq[r] = *reinterpret_cast<const float4*>(&wsm[r][j]);  // LDS broadcast b128
        float4 hv[4];
        #pragma unroll
        for (int k = 0; k < 4; ++k)
            hv[k] = reinterpret_cast<const float4*>(hidden + (size_t)(j + k) * M_DIM)[c4];
        #pragma unroll
        for (int r = 0; r < 4; ++r) {
            #pragma unroll
            for (int k = 0; k < 4; ++k) {
                const float wc = fcomp(wq[r], k);
                acc[r].x += wc * hv[k].x;
                acc[r].y += wc * hv[k].y;
                acc[r].z += wc * hv[k].z;
                acc[r].w += wc * hv[k].w;
            }
        }
    }

    #pragma unroll
    for (int r = 0; r < 4; ++r) part[r][h][c4] = acc[r];
    __syncthreads();

    if (t < 128) {
        const int r = t >> 5;
        const int c = t & 31;
        float4 sum = part[r][0][c];
        #pragma unroll
        for (int hh = 1; hh < 8; ++hh) {
            const float4 p = part[r][hh][c];
            sum.x += p.x; sum.y += p.y; sum.z += p.z; sum.w += p.w;
        }
        reinterpret_cast<float4*>(out + (size_t)(i0 + r) * M_DIM)[c] = sum;
    }
}

// ---------------------------------------------------------------------------
extern "C" void kernel_launch(void* const* d_in, const int* in_sizes, int n_in,
                              void* d_out, int out_size, void* d_ws, size_t ws_size,
                              hipStream_t stream) {
    const float* hidden = (const float*)d_in[0];   // [1024,128]
    const float* rela   = (const float*)d_in[1];   // [1024,1024,128]
    // d_in[2] corr_index: unused by the reference
    const int*   nei    = (const int*)d_in[3];     // [1024,1024]
    const float* att_w  = (const float*)d_in[4];   // [128]
    const float* att_b  = (const float*)d_in[5];   // [1]
    float* out    = (float*)d_out;                 // [1024,128]
    float* scores = (float*)d_ws;                  // [1024*1024] fp32 = 4 MB scratch

    // 16384 waves, 64 pairs each = 1M pairs
    scores_kernel<<<4096, 256, 0, stream>>>(rela, nei, att_w, att_b, scores);
    attn_kernel<<<P_DIM / 4, 256, 0, stream>>>(scores, nei, hidden, out);
}